// Round 15
// baseline (381.261 us; speedup 1.0000x reference)
//
#include <hip/hip_runtime.h>
#include <hip/hip_bf16.h>

#define B_SZ    2
#define L_SEQ   2048
#define D_MODEL 384
#define D_INNER 768
#define D_STATE 16
#define DT_RANK 24
#define ML      (B_SZ * L_SEQ)   // 4096 rows
#define NCHUNK  64
#define CHLEN   (L_SEQ / NCHUNK) // 32

typedef __hip_bfloat16 bf16;
typedef __attribute__((ext_vector_type(8))) short bf16x8;
typedef __attribute__((ext_vector_type(4))) float f32x4;
typedef __attribute__((ext_vector_type(8))) float f32x8;

// ---------------------------------------------------------------------------
// in_proj GEMM (64x64, R13 LDS-transpose epilogue) + fused prologue:
//  - zeroing of x_dbl (ML*56), d_out (ML*384, f32x4/thread) and dcnt[64]
//  - R14 one-shot weight convert+transpose: Wto[384][768], Wtx[56][768]
//    bf16 in exact Bs[n][k] staging layout (same RNE conversion ->
//    bit-identical staged values).
// R6 lesson: keep 64x64 tile at K=384.
// ---------------------------------------------------------------------------
__global__ __launch_bounds__(256)
void gemm_inproj(const float* __restrict__ Af, const float* __restrict__ W,
                 const float* __restrict__ xpw, const float* __restrict__ opw,
                 bf16* __restrict__ outb0, bf16* __restrict__ outb1,
                 float* __restrict__ xdbl_zero, float* __restrict__ dout_zero,
                 bf16* __restrict__ Wtx, bf16* __restrict__ Wto,
                 unsigned int* __restrict__ dcnt)
{
    __shared__ __attribute__((aligned(16))) short As[64][72];
    __shared__ __attribute__((aligned(16))) short Bs[64][72];
    const int tid  = threadIdx.x;

    // fused prologue (fire-and-forget)
    {
        int gidx = (blockIdx.y * gridDim.x + blockIdx.x) * 256 + tid; // 0..393215
        f32x4 z;
        z[0] = 0.f; z[1] = 0.f; z[2] = 0.f; z[3] = 0.f;
        *(f32x4*)&dout_zero[(size_t)gidx * 4] = z;       // ML*384 exactly
        if (gidx < ML * 56) xdbl_zero[gidx] = 0.f;       // ML*56
        if (gidx < 64) dcnt[gidx] = 0u;                  // R15 rendezvous ctr
        if (gidx < D_MODEL * D_INNER) {                  // Wto [384][768]
            int n = gidx / D_INNER, k = gidx - n * D_INNER;
            Wto[gidx] = __float2bfloat16(opw[(size_t)k * D_MODEL + n]);
        } else if (gidx < D_MODEL * D_INNER + 56 * D_INNER) {
            int g2 = gidx - D_MODEL * D_INNER;           // Wtx [56][768]
            int n = g2 / D_INNER, k = g2 - n * D_INNER;
            Wtx[g2] = __float2bfloat16(xpw[(size_t)k * 56 + n]);
        }
    }

    const int lane = tid & 63;
    const int wave = tid >> 6;
    const int wm   = (wave & 1) * 32;
    const int wn   = (wave >> 1) * 32;
    const int m0   = blockIdx.y * 64;
    const int n0   = blockIdx.x * 64;
    const int N    = 2 * D_INNER;        // 1536
    const int K    = D_MODEL;            // 384

    f32x4 acc[2][2];
#pragma unroll
    for (int i = 0; i < 2; i++)
#pragma unroll
        for (int j = 0; j < 2; j++)
#pragma unroll
            for (int r = 0; r < 4; r++) acc[i][j][r] = 0.f;

    for (int kt = 0; kt < K; kt += 64) {
        __syncthreads();
        // Stage A tile 64x64 (fp32 row-major -> bf16)
#pragma unroll
        for (int i = 0; i < 2; i++) {
            int c = tid + 256 * i;
            int m = c >> 3, k8 = (c & 7) * 8;
            f32x8 a = *(const f32x8*)&Af[(size_t)(m0 + m) * K + kt + k8];
            bf16x8 h;
#pragma unroll
            for (int j = 0; j < 8; j++)
                h[j] = (short)__bfloat16_as_ushort(__float2bfloat16(a[j]));
            *(bf16x8*)&As[m][k8] = h;
        }
        // Stage W tile 64x64 transposed into Bs[n][k], fp32 -> bf16
#pragma unroll
        for (int i = 0; i < 2; i++) {
            int c = tid + 256 * i;
            int n8 = (c & 7) * 8, k = c >> 3;
            f32x8 w = *(const f32x8*)&W[(size_t)(kt + k) * N + n0 + n8];
#pragma unroll
            for (int j = 0; j < 8; j++)
                Bs[n8 + j][k] = (short)__bfloat16_as_ushort(__float2bfloat16(w[j]));
        }
        __syncthreads();
#pragma unroll
        for (int ks = 0; ks < 2; ks++) {
            int kb = ks * 32 + (lane >> 4) * 8;
            bf16x8 a0 = *(const bf16x8*)&As[wm + (lane & 15)][kb];
            bf16x8 a1 = *(const bf16x8*)&As[wm + 16 + (lane & 15)][kb];
            bf16x8 b0 = *(const bf16x8*)&Bs[wn + (lane & 15)][kb];
            bf16x8 b1 = *(const bf16x8*)&Bs[wn + 16 + (lane & 15)][kb];
            acc[0][0] = __builtin_amdgcn_mfma_f32_16x16x32_bf16(a0, b0, acc[0][0], 0, 0, 0);
            acc[0][1] = __builtin_amdgcn_mfma_f32_16x16x32_bf16(a0, b1, acc[0][1], 0, 0, 0);
            acc[1][0] = __builtin_amdgcn_mfma_f32_16x16x32_bf16(a1, b0, acc[1][0], 0, 0, 0);
            acc[1][1] = __builtin_amdgcn_mfma_f32_16x16x32_bf16(a1, b1, acc[1][1], 0, 0, 0);
        }
    }

    // R13 epilogue: transpose through LDS, then coalesced stores along m.
    const bool zside = (n0 >= D_INNER);
    __syncthreads();                      // As/Bs dead; safe to overwrite
#pragma unroll
    for (int am = 0; am < 2; am++)
#pragma unroll
        for (int bn = 0; bn < 2; bn++)
#pragma unroll
            for (int r = 0; r < 4; r++) {
                int ml = wm + am * 16 + (lane >> 4) * 4 + r;   // 0..63
                int nl = wn + bn * 16 + (lane & 15);           // 0..63
                float v = acc[am][bn][r];
                if (zside) v = v / (1.f + __expf(-v));
                As[nl][ml] = (short)__bfloat16_as_ushort(__float2bfloat16(v));
            }
    __syncthreads();
    {
        bf16* outp = zside ? (outb1 + (size_t)(n0 - D_INNER) * ML)
                           : (outb0 + (size_t)n0 * ML);
#pragma unroll
        for (int i = 0; i < 2; i++) {
            int idx = tid + 256 * i;              // 0..511
            int nl = idx >> 3, m8 = (idx & 7) * 8;
            bf16x8 vrow = *(const bf16x8*)&As[nl][m8];
            *(bf16x8*)&outp[(size_t)nl * ML + m0 + m8] = vrow;
        }
    }
}

// ---------------------------------------------------------------------------
// x_proj GEMM, K-split x4, conv+silu fused into A-staging (R11) + R14
// vectorized Wtx staging + R15 LAST-FINISHER dt FUSION (dt_kernel dispatch
// removed, 5->4 dispatches; slot overhead ~13-15us per R7/R12 bracketing):
// the 4 kc-blocks of each m-range rendezvous on dcnt[m-block]; the 4th
// finisher (exactly one, atomic) computes dt = softplus(x_dbl[m][0:24] .
// dtw[:,dd] + dtb[dd]) for its 64 m x all 768 dd with the proven R12
// register/scalar structure. Coherence: release = threadfence + barrier
// before counter atomicAdd; winner re-fences and reads x_dbl via
// __hip_atomic_load(ACQUIRE, AGENT) (bypasses stale L1/per-XCD L2).
// Same fp32 sequence on identical complete sums -> bit-identical dt.
// ---------------------------------------------------------------------------
__global__ __launch_bounds__(256)
void gemm_xproj_conv(const bf16* __restrict__ Xraw, const bf16* __restrict__ Wtx,
                     const float* __restrict__ cw, const float* __restrict__ cb,
                     const float* __restrict__ dtw, const float* __restrict__ dtb,
                     bf16* __restrict__ xp_t, float* __restrict__ x_dbl,
                     bf16* __restrict__ dt_t, unsigned int* __restrict__ dcnt)
{
    __shared__ __attribute__((aligned(16))) short As[64][72];
    __shared__ __attribute__((aligned(16))) short Bs[64][72];
    __shared__ int sLast;
    const int tid  = threadIdx.x;
    const int lane = tid & 63;
    const int wave = tid >> 6;
    const int wm   = (wave & 1) * 32;
    const int wn   = (wave >> 1) * 32;
    const int m0   = blockIdx.y * 64;
    const int k0   = blockIdx.x * (768 / 4);     // 192-wide K chunk
    const int N    = 56;

    f32x4 acc[2][2];
#pragma unroll
    for (int i = 0; i < 2; i++)
#pragma unroll
        for (int j = 0; j < 2; j++)
#pragma unroll
            for (int r = 0; r < 4; r++) acc[i][j][r] = 0.f;

    for (int kt = k0; kt < k0 + 192; kt += 64) {
        __syncthreads();
        // A-staging with fused conv+silu: thread handles d=kt+k, m=m0+m8..+7
#pragma unroll
        for (int i = 0; i < 2; i++) {
            int c = tid + 256 * i;
            int m8 = (c & 7) * 8, k = c >> 3;
            const int d  = kt + k;
            const size_t row = (size_t)d * ML;
            const int mg = m0 + m8;                  // global m, 8-aligned
            const int l0 = mg & (L_SEQ - 1);         // l0+7 < L_SEQ

            bf16x8 cur = *(const bf16x8*)&Xraw[row + mg];
            bf16x8 prev;
            if (mg != 0) prev = *(const bf16x8*)&Xraw[row + mg - 8];
            else {
#pragma unroll
                for (int j = 0; j < 8; j++) prev[j] = 0;
            }
            const float w0 = cw[d * 4 + 0], w1 = cw[d * 4 + 1],
                        w2 = cw[d * 4 + 2], w3 = cw[d * 4 + 3], bias = cb[d];
            float wv[16];
#pragma unroll
            for (int j = 0; j < 8; j++) {
                wv[j]     = __uint_as_float(((unsigned)(unsigned short)prev[j]) << 16);
                wv[j + 8] = __uint_as_float(((unsigned)(unsigned short)cur[j]) << 16);
            }
            bf16x8 out;
#pragma unroll
            for (int o = 0; o < 8; o++) {
                int l = l0 + o;
                float s = bias;
                if (l >= 3) {
                    s += w0 * wv[5 + o] + w1 * wv[6 + o] + w2 * wv[7 + o] + w3 * wv[8 + o];
                } else {
                    if (l - 3 >= 0) s += w0 * wv[5 + o];
                    if (l - 2 >= 0) s += w1 * wv[6 + o];
                    if (l - 1 >= 0) s += w2 * wv[7 + o];
                    s += w3 * wv[8 + o];
                }
                float act = s / (1.f + __expf(-s));
                out[o] = (short)__bfloat16_as_ushort(__float2bfloat16(act));
                As[m8 + o][k] = out[o];
            }
            *(bf16x8*)&xp_t[row + mg] = out;     // materialize for scan (once)
        }
        // W-staging from Wtx (pre-transposed bf16): fully vectorized
#pragma unroll
        for (int i = 0; i < 2; i++) {
            int c = tid + 256 * i;
            int n = c >> 3, k8 = (c & 7) * 8;
            if (n < N) {
                *(bf16x8*)&Bs[n][k8] =
                    *(const bf16x8*)&Wtx[(size_t)n * D_INNER + kt + k8];
            } else {
                bf16x8 zz;
#pragma unroll
                for (int j = 0; j < 8; j++) zz[j] = 0;
                *(bf16x8*)&Bs[n][k8] = zz;
            }
        }
        __syncthreads();
#pragma unroll
        for (int ks = 0; ks < 2; ks++) {
            int kb = ks * 32 + (lane >> 4) * 8;
            bf16x8 a0 = *(const bf16x8*)&As[wm + (lane & 15)][kb];
            bf16x8 a1 = *(const bf16x8*)&As[wm + 16 + (lane & 15)][kb];
            bf16x8 b0 = *(const bf16x8*)&Bs[wn + (lane & 15)][kb];
            bf16x8 b1 = *(const bf16x8*)&Bs[wn + 16 + (lane & 15)][kb];
            acc[0][0] = __builtin_amdgcn_mfma_f32_16x16x32_bf16(a0, b0, acc[0][0], 0, 0, 0);
            acc[0][1] = __builtin_amdgcn_mfma_f32_16x16x32_bf16(a0, b1, acc[0][1], 0, 0, 0);
            acc[1][0] = __builtin_amdgcn_mfma_f32_16x16x32_bf16(a1, b0, acc[1][0], 0, 0, 0);
            acc[1][1] = __builtin_amdgcn_mfma_f32_16x16x32_bf16(a1, b1, acc[1][1], 0, 0, 0);
        }
    }

#pragma unroll
    for (int am = 0; am < 2; am++)
#pragma unroll
        for (int bn = 0; bn < 2; bn++)
#pragma unroll
            for (int r = 0; r < 4; r++) {
                int m = m0 + wm + am * 16 + (lane >> 4) * 4 + r;
                int n = wn + bn * 16 + (lane & 15);
                if (n < N)
                    atomicAdd(&x_dbl[(size_t)m * N + n], acc[am][bn][r]);
            }

    // ---- R15: last-finisher dt computation -------------------------------
    __threadfence();                      // release my x_dbl atomics
    __syncthreads();                      // all threads done + fenced
    if (tid == 0) {
        unsigned prev = atomicAdd(&dcnt[blockIdx.y], 1u);
        sLast = (prev == 3u);
    }
    __syncthreads();
    if (sLast) {
        __threadfence();                  // acquire side (conservative)
        const int m = m0 + lane;          // lane owns row m
        float xs[24];
#pragma unroll
        for (int r = 0; r < 24; r++)
            xs[r] = __hip_atomic_load(&x_dbl[(size_t)m * 56 + r],
                                      __ATOMIC_ACQUIRE, __HIP_MEMORY_SCOPE_AGENT);
        const int wvq = __builtin_amdgcn_readfirstlane(wave);   // 0..3, SGPR
        for (int i = 0; i < 192; i++) {
            const int dd = wvq * 192 + i;       // wave-uniform -> s_loads
            float a2 = dtb[dd];
#pragma unroll
            for (int r = 0; r < 24; r++)
                a2 += xs[r] * dtw[r * D_INNER + dd];
            float sp = fmaxf(a2, 0.f) + log1pf(__expf(-fabsf(a2)));
            dt_t[(size_t)dd * ML + m] = __float2bfloat16(sp);
        }
    }
}

// ---------------------------------------------------------------------------
// out_proj GEMM, K-split x4 (R8) + R14 W-staging from pre-transposed Wto
// [384][768] bf16. grid (6, 64, 4). d_out zeroed by gemm_inproj prologue.
// ---------------------------------------------------------------------------
__global__ __launch_bounds__(256)
void gemm_outproj_split(const bf16* __restrict__ At, const bf16* __restrict__ Wto,
                        float* __restrict__ outf)
{
    __shared__ __attribute__((aligned(16))) short As[64][72];
    __shared__ __attribute__((aligned(16))) short Bs[64][72];
    const int tid  = threadIdx.x;
    const int lane = tid & 63;
    const int wave = tid >> 6;
    const int wm   = (wave & 1) * 32;
    const int wn   = (wave >> 1) * 32;
    const int n0   = blockIdx.x * 64;            // 0..320
    const int m0   = blockIdx.y * 64;
    const int k0   = blockIdx.z * (768 / 4);     // 192-wide K chunk

    f32x4 acc[2][2];
#pragma unroll
    for (int i = 0; i < 2; i++)
#pragma unroll
        for (int j = 0; j < 2; j++)
#pragma unroll
            for (int r = 0; r < 4; r++) acc[i][j][r] = 0.f;

    for (int kt = k0; kt < k0 + 192; kt += 64) {
        __syncthreads();
#pragma unroll
        for (int i = 0; i < 2; i++) {
            int c = tid + 256 * i;
            int m8 = (c & 7) * 8, k = c >> 3;
            bf16x8 a = *(const bf16x8*)&At[(size_t)(kt + k) * ML + m0 + m8];
#pragma unroll
            for (int j = 0; j < 8; j++) As[m8 + j][k] = a[j];
        }
        // W-staging from Wto (pre-transposed bf16): fully vectorized
#pragma unroll
        for (int i = 0; i < 2; i++) {
            int c = tid + 256 * i;
            int n = c >> 3, k8 = (c & 7) * 8;
            *(bf16x8*)&Bs[n][k8] =
                *(const bf16x8*)&Wto[(size_t)(n0 + n) * D_INNER + kt + k8];
        }
        __syncthreads();
#pragma unroll
        for (int ks = 0; ks < 2; ks++) {
            int kb = ks * 32 + (lane >> 4) * 8;
            bf16x8 a0 = *(const bf16x8*)&As[wm + (lane & 15)][kb];
            bf16x8 a1 = *(const bf16x8*)&As[wm + 16 + (lane & 15)][kb];
            bf16x8 b0 = *(const bf16x8*)&Bs[wn + (lane & 15)][kb];
            bf16x8 b1 = *(const bf16x8*)&Bs[wn + 16 + (lane & 15)][kb];
            acc[0][0] = __builtin_amdgcn_mfma_f32_16x16x32_bf16(a0, b0, acc[0][0], 0, 0, 0);
            acc[0][1] = __builtin_amdgcn_mfma_f32_16x16x32_bf16(a0, b1, acc[0][1], 0, 0, 0);
            acc[1][0] = __builtin_amdgcn_mfma_f32_16x16x32_bf16(a1, b0, acc[1][0], 0, 0, 0);
            acc[1][1] = __builtin_amdgcn_mfma_f32_16x16x32_bf16(a1, b1, acc[1][1], 0, 0, 0);
        }
    }

#pragma unroll
    for (int am = 0; am < 2; am++)
#pragma unroll
        for (int bn = 0; bn < 2; bn++)
#pragma unroll
            for (int r = 0; r < 4; r++) {
                int m = m0 + wm + am * 16 + (lane >> 4) * 4 + r;
                int n = n0 + wn + bn * 16 + (lane & 15);
                atomicAdd(&outf[(size_t)m * D_MODEL + n], acc[am][bn][r]);
            }
}

// ---------------------------------------------------------------------------
// Chunk-parallel selective scan (R0-verbatim, green, 74-76us). FROZEN.
// R1-R8: every edit (reg-latch, hoisted loads, transposed B/C, dt fusion,
// even a 1-line zeroing prologue) regresses 6..54us.
// ---------------------------------------------------------------------------
__global__ __launch_bounds__(1024)
void scan_kernel(const bf16* __restrict__ dt_t, const bf16* __restrict__ xp_t,
                 const float* __restrict__ x_dbl, const bf16* __restrict__ zs_t,
                 const float* __restrict__ A_log, const float* __restrict__ Dp,
                 bf16* __restrict__ y_t)
{
    __shared__ float sP[NCHUNK][D_STATE + 1];
    __shared__ float sH[NCHUNK][D_STATE + 1];
    const int tid = threadIdx.x;
    const int c = tid >> 4;           // chunk 0..63
    const int n = tid & 15;           // state 0..15
    const int g = blockIdx.x;         // (b,d)
    const int b = g / D_INNER;
    const int d = g % D_INNER;
    const float A = -__expf(A_log[d * D_STATE + n]);
    const size_t base_t = (size_t)d * ML + (size_t)b * L_SEQ + (size_t)c * CHLEN;
    const size_t base_m = (size_t)b * L_SEQ + (size_t)c * CHLEN;

    float h = 0.f, P = 1.f;
#pragma unroll
    for (int g2 = 0; g2 < 2; g2++) {
        bf16x8 vdt0 = *(const bf16x8*)&dt_t[base_t + g2 * 16];
        bf16x8 vdt1 = *(const bf16x8*)&dt_t[base_t + g2 * 16 + 8];
        bf16x8 vxp0 = *(const bf16x8*)&xp_t[base_t + g2 * 16];
        bf16x8 vxp1 = *(const bf16x8*)&xp_t[base_t + g2 * 16 + 8];
#pragma unroll
        for (int k = 0; k < 16; k++) {
            const int j = g2 * 16 + k;
            short sdt = (k < 8) ? vdt0[k & 7] : vdt1[k & 7];
            short sxp = (k < 8) ? vxp0[k & 7] : vxp1[k & 7];
            float dtv = __uint_as_float(((unsigned)(unsigned short)sdt) << 16);
            float xpv = __uint_as_float(((unsigned)(unsigned short)sxp) << 16);
            float Bn  = x_dbl[(base_m + j) * 56 + DT_RANK + n];
            float aj = __expf(dtv * A);
            h = aj * h + Bn * (dtv * xpv);
            P *= aj;
        }
    }
    sP[c][n] = P;
    sH[c][n] = h;
    __syncthreads();

    // Phase 2: in-wave Kogge-Stone. Wave w (of 16) scans the 64 chunks of
    // state n=w; lane = chunk. Composition: h = p*h_prev + h; p = p*p_prev.
    {
        const int wv = tid >> 6;      // wave id 0..15 == state
        const int ln = tid & 63;      // lane == chunk
        float p = sP[ln][wv];
        float hh = sH[ln][wv];
#pragma unroll
        for (int s = 1; s < NCHUNK; s <<= 1) {
            float p2 = __shfl_up(p, s);
            float h2 = __shfl_up(hh, s);
            if (ln >= s) { hh = p * h2 + hh; p = p * p2; }
        }
        sP[ln][wv] = p;
        sH[ln][wv] = hh;
    }
    __syncthreads();
    const float hinit = (c == 0) ? 0.f : sH[c - 1][n];

    // Phase 3: corrected re-scan + butterfly reduce + select-latch store
    const float Dd = Dp[d];
    h = hinit;
#pragma unroll
    for (int g2 = 0; g2 < 2; g2++) {
        bf16x8 vdt0 = *(const bf16x8*)&dt_t[base_t + g2 * 16];
        bf16x8 vdt1 = *(const bf16x8*)&dt_t[base_t + g2 * 16 + 8];
        bf16x8 vxp0 = *(const bf16x8*)&xp_t[base_t + g2 * 16];
        bf16x8 vxp1 = *(const bf16x8*)&xp_t[base_t + g2 * 16 + 8];
        float ymine = 0.f, xmine = 0.f;
#pragma unroll
        for (int k = 0; k < 16; k++) {
            const int j = g2 * 16 + k;
            short sdt = (k < 8) ? vdt0[k & 7] : vdt1[k & 7];
            short sxp = (k < 8) ? vxp0[k & 7] : vxp1[k & 7];
            float dtv = __uint_as_float(((unsigned)(unsigned short)sdt) << 16);
            float xpv = __uint_as_float(((unsigned)(unsigned short)sxp) << 16);
            float Bn  = x_dbl[(base_m + j) * 56 + DT_RANK + n];
            float aj = __expf(dtv * A);
            h = aj * h + Bn * (dtv * xpv);
            float Cn = x_dbl[(base_m + j) * 56 + DT_RANK + D_STATE + n];
            float yv = h * Cn;
            yv += __shfl_xor(yv, 1);
            yv += __shfl_xor(yv, 2);
            yv += __shfl_xor(yv, 4);
            yv += __shfl_xor(yv, 8);
            // all 16 lanes hold the full sum; lane n keeps step g2*16+n
            ymine = (k == n) ? yv : ymine;
            xmine = (k == n) ? xpv : xmine;
        }
        const int j = g2 * 16 + n;
        float zsv = __bfloat162float(zs_t[base_t + j]);
        y_t[base_t + j] = __float2bfloat16((ymine + xmine * Dd) * zsv);
    }
}

// ---------------------------------------------------------------------------
extern "C" void kernel_launch(void* const* d_in, const int* in_sizes, int n_in,
                              void* d_out, int out_size, void* d_ws, size_t ws_size,
                              hipStream_t stream)
{
    const float* x         = (const float*)d_in[0];
    const float* in_proj_w = (const float*)d_in[1];
    const float* conv_w    = (const float*)d_in[2];
    const float* conv_b    = (const float*)d_in[3];
    const float* x_proj_w  = (const float*)d_in[4];
    const float* dt_proj_w = (const float*)d_in[5];
    const float* dt_proj_b = (const float*)d_in[6];
    const float* A_log     = (const float*)d_in[7];
    const float* Dvec      = (const float*)d_in[8];
    const float* out_proj_w= (const float*)d_in[9];

    // workspace: 4x bf16 [768][ML] + x_dbl + Wto/Wtx + dcnt (~27 MB)
    bf16* xp_raw_t = (bf16*)d_ws;                        // [768][ML] (reused as y_t)
    bf16* zs_t     = xp_raw_t + (size_t)ML * D_INNER;    // [768][ML] silu(z)
    bf16* xp_t     = zs_t     + (size_t)ML * D_INNER;    // [768][ML]
    bf16* dt_t     = xp_t     + (size_t)ML * D_INNER;    // [768][ML]
    float* x_dbl   = (float*)(dt_t + (size_t)ML * D_INNER); // [ML][56] fp32
    bf16* Wto      = (bf16*)(x_dbl + (size_t)ML * 56);   // [384][768] bf16
    bf16* Wtx      = Wto + (size_t)D_MODEL * D_INNER;    // [56][768] bf16
    unsigned int* dcnt = (unsigned int*)(Wtx + (size_t)56 * D_INNER); // [64]
    bf16* y_t      = xp_raw_t;                           // alias (dead after xproj')

    dim3 blk(256);

    // 1) in_proj (64x64, LDS-transpose epilogue) + fused zeroing + W pre-transpose
    gemm_inproj<<<dim3(2 * D_INNER / 64, ML / 64), blk, 0, stream>>>(
        x, in_proj_w, x_proj_w, out_proj_w, xp_raw_t, zs_t, x_dbl, (float*)d_out,
        Wtx, Wto, dcnt);

    // 2) x_proj with conv+silu fused into A-staging + R15 last-finisher dt
    //    (dt_kernel dispatch removed: 4 total dispatches)
    gemm_xproj_conv<<<dim3(4, ML / 64), blk, 0, stream>>>(
        xp_raw_t, Wtx, conv_w, conv_b, dt_proj_w, dt_proj_b, xp_t, x_dbl,
        dt_t, dcnt);

    // 3) selective scan (R0-verbatim, FROZEN) -> y_t
    scan_kernel<<<B_SZ * D_INNER, 1024, 0, stream>>>(
        dt_t, xp_t, x_dbl, zs_t, A_log, Dvec, y_t);

    // 4) out_proj, K-split x4 (Wto pre-staged bf16): atomics into zeroed d_out
    gemm_outproj_split<<<dim3(D_MODEL / 64, ML / 64, 4), blk, 0, stream>>>(
        y_t, Wto, (float*)d_out);
}

// Round 16
// 220.383 us; speedup vs baseline: 1.7300x; 1.7300x over previous
//
#include <hip/hip_runtime.h>
#include <hip/hip_bf16.h>

#define B_SZ    2
#define L_SEQ   2048
#define D_MODEL 384
#define D_INNER 768
#define D_STATE 16
#define DT_RANK 24
#define ML      (B_SZ * L_SEQ)   // 4096 rows
#define NCHUNK  64
#define CHLEN   (L_SEQ / NCHUNK) // 32

typedef __hip_bfloat16 bf16;
typedef __attribute__((ext_vector_type(8))) short bf16x8;
typedef __attribute__((ext_vector_type(4))) float f32x4;
typedef __attribute__((ext_vector_type(8))) float f32x8;

// ---------------------------------------------------------------------------
// R16 = R14 verbatim (session best, 221.1 us). R15's last-finisher dt fusion
// regressed to 381us: the 192-deep dynamic loop serialized 4608 dependent
// s_loads (~375us tail on 64 near-idle blocks). Cross-block fusion with
// serial tails is poison; prologue fusion (proven 4x here) is not.
// ---------------------------------------------------------------------------

// ---------------------------------------------------------------------------
// in_proj GEMM (64x64, R13 LDS-transpose epilogue) + fused prologue:
//  - zeroing of x_dbl (ML*56) and d_out (ML*384, f32x4/thread exact cover)
//  - R14 one-shot weight convert+transpose: Wto[384][768], Wtx[56][768]
//    bf16 in exact Bs[n][k] staging layout (same RNE conversion ->
//    bit-identical staged values).
// R6 lesson: keep 64x64 tile at K=384.
// ---------------------------------------------------------------------------
__global__ __launch_bounds__(256)
void gemm_inproj(const float* __restrict__ Af, const float* __restrict__ W,
                 const float* __restrict__ xpw, const float* __restrict__ opw,
                 bf16* __restrict__ outb0, bf16* __restrict__ outb1,
                 float* __restrict__ xdbl_zero, float* __restrict__ dout_zero,
                 bf16* __restrict__ Wtx, bf16* __restrict__ Wto)
{
    __shared__ __attribute__((aligned(16))) short As[64][72];
    __shared__ __attribute__((aligned(16))) short Bs[64][72];
    const int tid  = threadIdx.x;

    // fused prologue (fire-and-forget)
    {
        int gidx = (blockIdx.y * gridDim.x + blockIdx.x) * 256 + tid; // 0..393215
        f32x4 z;
        z[0] = 0.f; z[1] = 0.f; z[2] = 0.f; z[3] = 0.f;
        *(f32x4*)&dout_zero[(size_t)gidx * 4] = z;       // ML*384 exactly
        if (gidx < ML * 56) xdbl_zero[gidx] = 0.f;       // ML*56
        if (gidx < D_MODEL * D_INNER) {                  // Wto [384][768]
            int n = gidx / D_INNER, k = gidx - n * D_INNER;
            Wto[gidx] = __float2bfloat16(opw[(size_t)k * D_MODEL + n]);
        } else if (gidx < D_MODEL * D_INNER + 56 * D_INNER) {
            int g2 = gidx - D_MODEL * D_INNER;           // Wtx [56][768]
            int n = g2 / D_INNER, k = g2 - n * D_INNER;
            Wtx[g2] = __float2bfloat16(xpw[(size_t)k * 56 + n]);
        }
    }

    const int lane = tid & 63;
    const int wave = tid >> 6;
    const int wm   = (wave & 1) * 32;
    const int wn   = (wave >> 1) * 32;
    const int m0   = blockIdx.y * 64;
    const int n0   = blockIdx.x * 64;
    const int N    = 2 * D_INNER;        // 1536
    const int K    = D_MODEL;            // 384

    f32x4 acc[2][2];
#pragma unroll
    for (int i = 0; i < 2; i++)
#pragma unroll
        for (int j = 0; j < 2; j++)
#pragma unroll
            for (int r = 0; r < 4; r++) acc[i][j][r] = 0.f;

    for (int kt = 0; kt < K; kt += 64) {
        __syncthreads();
        // Stage A tile 64x64 (fp32 row-major -> bf16)
#pragma unroll
        for (int i = 0; i < 2; i++) {
            int c = tid + 256 * i;
            int m = c >> 3, k8 = (c & 7) * 8;
            f32x8 a = *(const f32x8*)&Af[(size_t)(m0 + m) * K + kt + k8];
            bf16x8 h;
#pragma unroll
            for (int j = 0; j < 8; j++)
                h[j] = (short)__bfloat16_as_ushort(__float2bfloat16(a[j]));
            *(bf16x8*)&As[m][k8] = h;
        }
        // Stage W tile 64x64 transposed into Bs[n][k], fp32 -> bf16
#pragma unroll
        for (int i = 0; i < 2; i++) {
            int c = tid + 256 * i;
            int n8 = (c & 7) * 8, k = c >> 3;
            f32x8 w = *(const f32x8*)&W[(size_t)(kt + k) * N + n0 + n8];
#pragma unroll
            for (int j = 0; j < 8; j++)
                Bs[n8 + j][k] = (short)__bfloat16_as_ushort(__float2bfloat16(w[j]));
        }
        __syncthreads();
#pragma unroll
        for (int ks = 0; ks < 2; ks++) {
            int kb = ks * 32 + (lane >> 4) * 8;
            bf16x8 a0 = *(const bf16x8*)&As[wm + (lane & 15)][kb];
            bf16x8 a1 = *(const bf16x8*)&As[wm + 16 + (lane & 15)][kb];
            bf16x8 b0 = *(const bf16x8*)&Bs[wn + (lane & 15)][kb];
            bf16x8 b1 = *(const bf16x8*)&Bs[wn + 16 + (lane & 15)][kb];
            acc[0][0] = __builtin_amdgcn_mfma_f32_16x16x32_bf16(a0, b0, acc[0][0], 0, 0, 0);
            acc[0][1] = __builtin_amdgcn_mfma_f32_16x16x32_bf16(a0, b1, acc[0][1], 0, 0, 0);
            acc[1][0] = __builtin_amdgcn_mfma_f32_16x16x32_bf16(a1, b0, acc[1][0], 0, 0, 0);
            acc[1][1] = __builtin_amdgcn_mfma_f32_16x16x32_bf16(a1, b1, acc[1][1], 0, 0, 0);
        }
    }

    // R13 epilogue: transpose through LDS, then coalesced stores along m.
    const bool zside = (n0 >= D_INNER);
    __syncthreads();                      // As/Bs dead; safe to overwrite
#pragma unroll
    for (int am = 0; am < 2; am++)
#pragma unroll
        for (int bn = 0; bn < 2; bn++)
#pragma unroll
            for (int r = 0; r < 4; r++) {
                int ml = wm + am * 16 + (lane >> 4) * 4 + r;   // 0..63
                int nl = wn + bn * 16 + (lane & 15);           // 0..63
                float v = acc[am][bn][r];
                if (zside) v = v / (1.f + __expf(-v));
                As[nl][ml] = (short)__bfloat16_as_ushort(__float2bfloat16(v));
            }
    __syncthreads();
    {
        bf16* outp = zside ? (outb1 + (size_t)(n0 - D_INNER) * ML)
                           : (outb0 + (size_t)n0 * ML);
#pragma unroll
        for (int i = 0; i < 2; i++) {
            int idx = tid + 256 * i;              // 0..511
            int nl = idx >> 3, m8 = (idx & 7) * 8;
            bf16x8 vrow = *(const bf16x8*)&As[nl][m8];
            *(bf16x8*)&outp[(size_t)nl * ML + m0 + m8] = vrow;
        }
    }
}

// ---------------------------------------------------------------------------
// x_proj GEMM, K-split x4, conv+silu fused into A-staging (R11, best) +
// R14 W-staging from pre-transposed Wtx [56][768] bf16: one bf16x8 load ->
// one b128 LDS write (was f32x8 + 8 cvt + 8 scalar ds_write_b16).
// Atomics into x_dbl [ML][56] (zeroed by in_proj prologue).
// ---------------------------------------------------------------------------
__global__ __launch_bounds__(256)
void gemm_xproj_conv(const bf16* __restrict__ Xraw, const bf16* __restrict__ Wtx,
                     const float* __restrict__ cw, const float* __restrict__ cb,
                     bf16* __restrict__ xp_t, float* __restrict__ outf)
{
    __shared__ __attribute__((aligned(16))) short As[64][72];
    __shared__ __attribute__((aligned(16))) short Bs[64][72];
    const int tid  = threadIdx.x;
    const int lane = tid & 63;
    const int wave = tid >> 6;
    const int wm   = (wave & 1) * 32;
    const int wn   = (wave >> 1) * 32;
    const int m0   = blockIdx.y * 64;
    const int k0   = blockIdx.x * (768 / 4);     // 192-wide K chunk
    const int N    = 56;

    f32x4 acc[2][2];
#pragma unroll
    for (int i = 0; i < 2; i++)
#pragma unroll
        for (int j = 0; j < 2; j++)
#pragma unroll
            for (int r = 0; r < 4; r++) acc[i][j][r] = 0.f;

    for (int kt = k0; kt < k0 + 192; kt += 64) {
        __syncthreads();
        // A-staging with fused conv+silu: thread handles d=kt+k, m=m0+m8..+7
#pragma unroll
        for (int i = 0; i < 2; i++) {
            int c = tid + 256 * i;
            int m8 = (c & 7) * 8, k = c >> 3;
            const int d  = kt + k;
            const size_t row = (size_t)d * ML;
            const int mg = m0 + m8;                  // global m, 8-aligned
            const int l0 = mg & (L_SEQ - 1);         // l0+7 < L_SEQ

            bf16x8 cur = *(const bf16x8*)&Xraw[row + mg];
            bf16x8 prev;
            if (mg != 0) prev = *(const bf16x8*)&Xraw[row + mg - 8];
            else {
#pragma unroll
                for (int j = 0; j < 8; j++) prev[j] = 0;
            }
            const float w0 = cw[d * 4 + 0], w1 = cw[d * 4 + 1],
                        w2 = cw[d * 4 + 2], w3 = cw[d * 4 + 3], bias = cb[d];
            float wv[16];
#pragma unroll
            for (int j = 0; j < 8; j++) {
                wv[j]     = __uint_as_float(((unsigned)(unsigned short)prev[j]) << 16);
                wv[j + 8] = __uint_as_float(((unsigned)(unsigned short)cur[j]) << 16);
            }
            bf16x8 out;
#pragma unroll
            for (int o = 0; o < 8; o++) {
                int l = l0 + o;
                float s = bias;
                if (l >= 3) {
                    s += w0 * wv[5 + o] + w1 * wv[6 + o] + w2 * wv[7 + o] + w3 * wv[8 + o];
                } else {
                    if (l - 3 >= 0) s += w0 * wv[5 + o];
                    if (l - 2 >= 0) s += w1 * wv[6 + o];
                    if (l - 1 >= 0) s += w2 * wv[7 + o];
                    s += w3 * wv[8 + o];
                }
                float act = s / (1.f + __expf(-s));
                out[o] = (short)__bfloat16_as_ushort(__float2bfloat16(act));
                As[m8 + o][k] = out[o];
            }
            *(bf16x8*)&xp_t[row + mg] = out;     // materialize for scan (once)
        }
        // W-staging from Wtx (pre-transposed bf16): fully vectorized
#pragma unroll
        for (int i = 0; i < 2; i++) {
            int c = tid + 256 * i;
            int n = c >> 3, k8 = (c & 7) * 8;
            if (n < N) {
                *(bf16x8*)&Bs[n][k8] =
                    *(const bf16x8*)&Wtx[(size_t)n * D_INNER + kt + k8];
            } else {
                bf16x8 zz;
#pragma unroll
                for (int j = 0; j < 8; j++) zz[j] = 0;
                *(bf16x8*)&Bs[n][k8] = zz;
            }
        }
        __syncthreads();
#pragma unroll
        for (int ks = 0; ks < 2; ks++) {
            int kb = ks * 32 + (lane >> 4) * 8;
            bf16x8 a0 = *(const bf16x8*)&As[wm + (lane & 15)][kb];
            bf16x8 a1 = *(const bf16x8*)&As[wm + 16 + (lane & 15)][kb];
            bf16x8 b0 = *(const bf16x8*)&Bs[wn + (lane & 15)][kb];
            bf16x8 b1 = *(const bf16x8*)&Bs[wn + 16 + (lane & 15)][kb];
            acc[0][0] = __builtin_amdgcn_mfma_f32_16x16x32_bf16(a0, b0, acc[0][0], 0, 0, 0);
            acc[0][1] = __builtin_amdgcn_mfma_f32_16x16x32_bf16(a0, b1, acc[0][1], 0, 0, 0);
            acc[1][0] = __builtin_amdgcn_mfma_f32_16x16x32_bf16(a1, b0, acc[1][0], 0, 0, 0);
            acc[1][1] = __builtin_amdgcn_mfma_f32_16x16x32_bf16(a1, b1, acc[1][1], 0, 0, 0);
        }
    }

#pragma unroll
    for (int am = 0; am < 2; am++)
#pragma unroll
        for (int bn = 0; bn < 2; bn++)
#pragma unroll
            for (int r = 0; r < 4; r++) {
                int m = m0 + wm + am * 16 + (lane >> 4) * 4 + r;
                int n = wn + bn * 16 + (lane & 15);
                if (n < N)
                    atomicAdd(&outf[(size_t)m * N + n], acc[am][bn][r]);
            }
}

// ---------------------------------------------------------------------------
// out_proj GEMM, K-split x4 (R8) + R14 W-staging from pre-transposed Wto
// [384][768] bf16: one bf16x8 load -> one b128 LDS write per 8 elems.
// grid (6, 64, 4). d_out zeroed by gemm_inproj prologue.
// ---------------------------------------------------------------------------
__global__ __launch_bounds__(256)
void gemm_outproj_split(const bf16* __restrict__ At, const bf16* __restrict__ Wto,
                        float* __restrict__ outf)
{
    __shared__ __attribute__((aligned(16))) short As[64][72];
    __shared__ __attribute__((aligned(16))) short Bs[64][72];
    const int tid  = threadIdx.x;
    const int lane = tid & 63;
    const int wave = tid >> 6;
    const int wm   = (wave & 1) * 32;
    const int wn   = (wave >> 1) * 32;
    const int n0   = blockIdx.x * 64;            // 0..320
    const int m0   = blockIdx.y * 64;
    const int k0   = blockIdx.z * (768 / 4);     // 192-wide K chunk

    f32x4 acc[2][2];
#pragma unroll
    for (int i = 0; i < 2; i++)
#pragma unroll
        for (int j = 0; j < 2; j++)
#pragma unroll
            for (int r = 0; r < 4; r++) acc[i][j][r] = 0.f;

    for (int kt = k0; kt < k0 + 192; kt += 64) {
        __syncthreads();
#pragma unroll
        for (int i = 0; i < 2; i++) {
            int c = tid + 256 * i;
            int m8 = (c & 7) * 8, k = c >> 3;
            bf16x8 a = *(const bf16x8*)&At[(size_t)(kt + k) * ML + m0 + m8];
#pragma unroll
            for (int j = 0; j < 8; j++) As[m8 + j][k] = a[j];
        }
        // W-staging from Wto (pre-transposed bf16): fully vectorized
#pragma unroll
        for (int i = 0; i < 2; i++) {
            int c = tid + 256 * i;
            int n = c >> 3, k8 = (c & 7) * 8;
            *(bf16x8*)&Bs[n][k8] =
                *(const bf16x8*)&Wto[(size_t)(n0 + n) * D_INNER + kt + k8];
        }
        __syncthreads();
#pragma unroll
        for (int ks = 0; ks < 2; ks++) {
            int kb = ks * 32 + (lane >> 4) * 8;
            bf16x8 a0 = *(const bf16x8*)&As[wm + (lane & 15)][kb];
            bf16x8 a1 = *(const bf16x8*)&As[wm + 16 + (lane & 15)][kb];
            bf16x8 b0 = *(const bf16x8*)&Bs[wn + (lane & 15)][kb];
            bf16x8 b1 = *(const bf16x8*)&Bs[wn + 16 + (lane & 15)][kb];
            acc[0][0] = __builtin_amdgcn_mfma_f32_16x16x32_bf16(a0, b0, acc[0][0], 0, 0, 0);
            acc[0][1] = __builtin_amdgcn_mfma_f32_16x16x32_bf16(a0, b1, acc[0][1], 0, 0, 0);
            acc[1][0] = __builtin_amdgcn_mfma_f32_16x16x32_bf16(a1, b0, acc[1][0], 0, 0, 0);
            acc[1][1] = __builtin_amdgcn_mfma_f32_16x16x32_bf16(a1, b1, acc[1][1], 0, 0, 0);
        }
    }

#pragma unroll
    for (int am = 0; am < 2; am++)
#pragma unroll
        for (int bn = 0; bn < 2; bn++)
#pragma unroll
            for (int r = 0; r < 4; r++) {
                int m = m0 + wm + am * 16 + (lane >> 4) * 4 + r;
                int n = n0 + wn + bn * 16 + (lane & 15);
                atomicAdd(&outf[(size_t)m * D_MODEL + n], acc[am][bn][r]);
            }
}

// ---------------------------------------------------------------------------
// dt = softplus(dt_r @ dt_proj_w + b) -- R12 register/scalar rewrite (WIN,
// -6.6us): lane owns row m (24 dt_r in VGPRs); wave owns 12 wave-uniform dd
// columns (readfirstlane -> SGPR) so dtw/dtb reads are scalar s_loads,
// FULLY UNROLLED (288 independent s_loads, pipelined -- R15 lesson: a
// 192-deep dynamic loop serializes them, 375us tail). Zero LDS.
// Bit-identical to R0 dt_kernel. Stores 128B-coalesced.
// ---------------------------------------------------------------------------
__global__ __launch_bounds__(256)
void dt_kernel(const float* __restrict__ x_dbl, const float* __restrict__ dtw,
               const float* __restrict__ dtb, bf16* __restrict__ dt_t)
{
    const int tid  = threadIdx.x;
    const int lane = tid & 63;
    const int wv   = __builtin_amdgcn_readfirstlane(tid >> 6);  // 0..3, SGPR
    const int m    = blockIdx.x * 64 + lane;
    const int d0   = blockIdx.y * 48 + wv * 12;                 // wave's dd base

    float xs[24];
    {
        const float* rowp = &x_dbl[(size_t)m * 56];
        f32x8 v0 = *(const f32x8*)&rowp[0];
        f32x8 v1 = *(const f32x8*)&rowp[8];
        f32x8 v2 = *(const f32x8*)&rowp[16];
#pragma unroll
        for (int j = 0; j < 8; j++) {
            xs[j] = v0[j]; xs[8 + j] = v1[j]; xs[16 + j] = v2[j];
        }
    }

#pragma unroll
    for (int i = 0; i < 12; i++) {
        const int dd = d0 + i;                 // wave-uniform -> scalar addr
        float acc = dtb[dd];
#pragma unroll
        for (int r = 0; r < 24; r++)
            acc += xs[r] * dtw[r * D_INNER + dd];
        float sp = fmaxf(acc, 0.f) + log1pf(__expf(-fabsf(acc)));
        dt_t[(size_t)dd * ML + m] = __float2bfloat16(sp);
    }
}

// ---------------------------------------------------------------------------
// Chunk-parallel selective scan (R0-verbatim, green, 74-76us). FROZEN.
// R1-R8: every edit (reg-latch, hoisted loads, transposed B/C, dt fusion,
// even a 1-line zeroing prologue) regresses 6..54us.
// ---------------------------------------------------------------------------
__global__ __launch_bounds__(1024)
void scan_kernel(const bf16* __restrict__ dt_t, const bf16* __restrict__ xp_t,
                 const float* __restrict__ x_dbl, const bf16* __restrict__ zs_t,
                 const float* __restrict__ A_log, const float* __restrict__ Dp,
                 bf16* __restrict__ y_t)
{
    __shared__ float sP[NCHUNK][D_STATE + 1];
    __shared__ float sH[NCHUNK][D_STATE + 1];
    const int tid = threadIdx.x;
    const int c = tid >> 4;           // chunk 0..63
    const int n = tid & 15;           // state 0..15
    const int g = blockIdx.x;         // (b,d)
    const int b = g / D_INNER;
    const int d = g % D_INNER;
    const float A = -__expf(A_log[d * D_STATE + n]);
    const size_t base_t = (size_t)d * ML + (size_t)b * L_SEQ + (size_t)c * CHLEN;
    const size_t base_m = (size_t)b * L_SEQ + (size_t)c * CHLEN;

    float h = 0.f, P = 1.f;
#pragma unroll
    for (int g2 = 0; g2 < 2; g2++) {
        bf16x8 vdt0 = *(const bf16x8*)&dt_t[base_t + g2 * 16];
        bf16x8 vdt1 = *(const bf16x8*)&dt_t[base_t + g2 * 16 + 8];
        bf16x8 vxp0 = *(const bf16x8*)&xp_t[base_t + g2 * 16];
        bf16x8 vxp1 = *(const bf16x8*)&xp_t[base_t + g2 * 16 + 8];
#pragma unroll
        for (int k = 0; k < 16; k++) {
            const int j = g2 * 16 + k;
            short sdt = (k < 8) ? vdt0[k & 7] : vdt1[k & 7];
            short sxp = (k < 8) ? vxp0[k & 7] : vxp1[k & 7];
            float dtv = __uint_as_float(((unsigned)(unsigned short)sdt) << 16);
            float xpv = __uint_as_float(((unsigned)(unsigned short)sxp) << 16);
            float Bn  = x_dbl[(base_m + j) * 56 + DT_RANK + n];
            float aj = __expf(dtv * A);
            h = aj * h + Bn * (dtv * xpv);
            P *= aj;
        }
    }
    sP[c][n] = P;
    sH[c][n] = h;
    __syncthreads();

    // Phase 2: in-wave Kogge-Stone. Wave w (of 16) scans the 64 chunks of
    // state n=w; lane = chunk. Composition: h = p*h_prev + h; p = p*p_prev.
    {
        const int wv = tid >> 6;      // wave id 0..15 == state
        const int ln = tid & 63;      // lane == chunk
        float p = sP[ln][wv];
        float hh = sH[ln][wv];
#pragma unroll
        for (int s = 1; s < NCHUNK; s <<= 1) {
            float p2 = __shfl_up(p, s);
            float h2 = __shfl_up(hh, s);
            if (ln >= s) { hh = p * h2 + hh; p = p * p2; }
        }
        sP[ln][wv] = p;
        sH[ln][wv] = hh;
    }
    __syncthreads();
    const float hinit = (c == 0) ? 0.f : sH[c - 1][n];

    // Phase 3: corrected re-scan + butterfly reduce + select-latch store
    const float Dd = Dp[d];
    h = hinit;
#pragma unroll
    for (int g2 = 0; g2 < 2; g2++) {
        bf16x8 vdt0 = *(const bf16x8*)&dt_t[base_t + g2 * 16];
        bf16x8 vdt1 = *(const bf16x8*)&dt_t[base_t + g2 * 16 + 8];
        bf16x8 vxp0 = *(const bf16x8*)&xp_t[base_t + g2 * 16];
        bf16x8 vxp1 = *(const bf16x8*)&xp_t[base_t + g2 * 16 + 8];
        float ymine = 0.f, xmine = 0.f;
#pragma unroll
        for (int k = 0; k < 16; k++) {
            const int j = g2 * 16 + k;
            short sdt = (k < 8) ? vdt0[k & 7] : vdt1[k & 7];
            short sxp = (k < 8) ? vxp0[k & 7] : vxp1[k & 7];
            float dtv = __uint_as_float(((unsigned)(unsigned short)sdt) << 16);
            float xpv = __uint_as_float(((unsigned)(unsigned short)sxp) << 16);
            float Bn  = x_dbl[(base_m + j) * 56 + DT_RANK + n];
            float aj = __expf(dtv * A);
            h = aj * h + Bn * (dtv * xpv);
            float Cn = x_dbl[(base_m + j) * 56 + DT_RANK + D_STATE + n];
            float yv = h * Cn;
            yv += __shfl_xor(yv, 1);
            yv += __shfl_xor(yv, 2);
            yv += __shfl_xor(yv, 4);
            yv += __shfl_xor(yv, 8);
            // all 16 lanes hold the full sum; lane n keeps step g2*16+n
            ymine = (k == n) ? yv : ymine;
            xmine = (k == n) ? xpv : xmine;
        }
        const int j = g2 * 16 + n;
        float zsv = __bfloat162float(zs_t[base_t + j]);
        y_t[base_t + j] = __float2bfloat16((ymine + xmine * Dd) * zsv);
    }
}

// ---------------------------------------------------------------------------
extern "C" void kernel_launch(void* const* d_in, const int* in_sizes, int n_in,
                              void* d_out, int out_size, void* d_ws, size_t ws_size,
                              hipStream_t stream)
{
    const float* x         = (const float*)d_in[0];
    const float* in_proj_w = (const float*)d_in[1];
    const float* conv_w    = (const float*)d_in[2];
    const float* conv_b    = (const float*)d_in[3];
    const float* x_proj_w  = (const float*)d_in[4];
    const float* dt_proj_w = (const float*)d_in[5];
    const float* dt_proj_b = (const float*)d_in[6];
    const float* A_log     = (const float*)d_in[7];
    const float* Dvec      = (const float*)d_in[8];
    const float* out_proj_w= (const float*)d_in[9];

    // workspace: 4x bf16 [768][ML] + x_dbl [ML][56] fp32 + Wto/Wtx bf16 (~27 MB)
    bf16* xp_raw_t = (bf16*)d_ws;                        // [768][ML] (reused as y_t)
    bf16* zs_t     = xp_raw_t + (size_t)ML * D_INNER;    // [768][ML] silu(z)
    bf16* xp_t     = zs_t     + (size_t)ML * D_INNER;    // [768][ML]
    bf16* dt_t     = xp_t     + (size_t)ML * D_INNER;    // [768][ML]
    float* x_dbl   = (float*)(dt_t + (size_t)ML * D_INNER); // [ML][56] fp32
    bf16* Wto      = (bf16*)(x_dbl + (size_t)ML * 56);   // [384][768] bf16
    bf16* Wtx      = Wto + (size_t)D_MODEL * D_INNER;    // [56][768] bf16
    bf16* y_t      = xp_raw_t;                           // alias (dead after xproj')

    dim3 blk(256);

    // 1) in_proj (64x64, LDS-transpose epilogue) + fused zeroing + W pre-transpose
    gemm_inproj<<<dim3(2 * D_INNER / 64, ML / 64), blk, 0, stream>>>(
        x, in_proj_w, x_proj_w, out_proj_w, xp_raw_t, zs_t, x_dbl, (float*)d_out,
        Wtx, Wto);

    // 2) x_proj with conv+silu fused into A-staging (Wtx pre-staged bf16;
    //    writes xp_t once, K-split x4 atomics into x_dbl)
    gemm_xproj_conv<<<dim3(4, ML / 64), blk, 0, stream>>>(
        xp_raw_t, Wtx, conv_w, conv_b, xp_t, x_dbl);

    // 3) dt_proj + softplus (register/scalar, bit-identical) -> dt_t
    dt_kernel<<<dim3(ML / 64, D_INNER / 48), blk, 0, stream>>>(
        x_dbl, dt_proj_w, dt_proj_b, dt_t);

    // 4) selective scan (R0-verbatim, FROZEN) -> y_t
    scan_kernel<<<B_SZ * D_INNER, 1024, 0, stream>>>(
        dt_t, xp_t, x_dbl, zs_t, A_log, Dvec, y_t);

    // 5) out_proj, K-split x4 (Wto pre-staged bf16): atomics into zeroed d_out
    gemm_outproj_split<<<dim3(D_MODEL / 64, ML / 64, 4), blk, 0, stream>>>(
        y_t, Wto, (float*)d_out);
}